// Round 4
// baseline (1680.331 us; speedup 1.0000x reference)
//
#include <hip/hip_runtime.h>
#include <stdint.h>

typedef short bfrag __attribute__((ext_vector_type(8)));   // 8 bf16 (4 VGPR)
typedef float facc4 __attribute__((ext_vector_type(4)));   // MFMA accumulator

__device__ __forceinline__ unsigned short f2bf(float x){
  union { float f; uint32_t u; } v; v.f = x;
  uint32_t r = v.u + 0x7FFFu + ((v.u >> 16) & 1u);   // RNE
  return (unsigned short)(r >> 16);
}
__device__ __forceinline__ float bf2f(unsigned short h){
  union { uint32_t u; float f; } v; v.u = ((uint32_t)h) << 16; return v.f;
}
__device__ __forceinline__ uint32_t pack2(unsigned short a, unsigned short b){
  return (uint32_t)a | ((uint32_t)b << 16);
}

// Plane-layout LDS offset: tile stored as 8 planes x ROWS x 16B fragments.
// plane = (part,kgroup) slot 0..7; within a plane, row's chunk position has
// its low-3 bits XOR'd by the plane id (same involution on write and read).
// Reads (fixed plane, 16 consecutive rows) are contiguous 256B -> conflict-
// free; writes (8 planes x row-pairs per quarter) spread over all banks.
__device__ __forceinline__ int lofs(int rows, int plane, int r){
  return (plane * rows + ((r & ~7) | ((r & 7) ^ plane))) * 16;
}

// ---------------------------------------------------------------------------
// Unified tiled GEMM.
// AMODE: 0 = A is f32, split to hi/lo inline (3-pass). 1 = A is pre-split bf16
//        pair (hi at A0, lo at A1), 3-pass. 2 = plain bf16 (1-pass, BK=64).
// CMODE: 0 = f32 output (ldc). 1 = qw split-interleaved ushort rows
//        [hi(1024)|lo(1024)] written to C (ldc fixed 2048).
// Planes: SPLIT -> 0-3 = hi k-groups, 4-7 = lo k-groups (BK=32).
//         PLAIN -> 0-7 = k-groups (BK=64).
// ---------------------------------------------------------------------------
template<int AMODE, int BM, int BN, int NW, int CMODE>
__global__ __launch_bounds__(NW*64, 2)
void gemm_kernel(const void* __restrict__ A0, const void* __restrict__ A1,
                 const unsigned short* __restrict__ B0,
                 const unsigned short* __restrict__ B1,
                 void* __restrict__ C,
                 int lda, int ldb, int ldc, int K,
                 long abstr, long bbstr, long cbstr)
{
  constexpr bool SPLIT = (AMODE <= 1);
  constexpr int  BK    = SPLIT ? 32 : 64;
  constexpr int  NT    = NW * 64;
  constexpr int  NWN   = BN / 64;
  constexpr int  NWM   = BM / 64;
  static_assert(NWM * NWN == NW, "wave grid");
  constexpr int  BUF   = (BM + BN) * 128;                  // 8 planes * rows * 16B, A+B
  constexpr int  BCPT  = BN * 8 / NT;                      // B 16B-chunks/thread
  constexpr int  ACPT  = (AMODE == 0) ? (BM * 4 / NT) : (BM * 8 / NT);
  constexpr int  AREG  = (AMODE == 0) ? 2 * ACPT : ACPT;

  __shared__ __align__(16) char smem[2 * BUF];

  const int tid = threadIdx.x;
  const int z   = blockIdx.z;
  const int m0  = blockIdx.x * BM;
  const int n0  = blockIdx.y * BN;

  const float* Af = nullptr;
  const unsigned short* Ahi = nullptr;
  const unsigned short* Alo = nullptr;
  if constexpr (AMODE == 0) {
    Af = (const float*)A0 + (size_t)z * (size_t)abstr;
  } else {
    Ahi = (const unsigned short*)A0 + (size_t)z * (size_t)abstr;
    if constexpr (AMODE == 1)
      Alo = (const unsigned short*)A1 + (size_t)z * (size_t)abstr;
  }
  const unsigned short* Bhi = B0 + (size_t)z * (size_t)bbstr;
  const unsigned short* Blo = nullptr;
  if constexpr (SPLIT) Blo = B1 + (size_t)z * (size_t)bbstr;

  uint4 areg[AREG];
  uint4 breg[BCPT];

  auto stage_load = [&](int kt){
    const int k0 = kt * BK;
    #pragma unroll
    for (int i = 0; i < BCPT; ++i){
      int ci = i * NT + tid;
      int row = ci >> 3, slot = ci & 7;
      const unsigned short* src; int kk;
      if constexpr (SPLIT) { src = (slot < 4) ? Bhi : Blo; kk = (slot & 3) * 8; }
      else                 { src = Bhi;                    kk = slot * 8; }
      breg[i] = *(const uint4*)(src + (size_t)(n0 + row) * ldb + k0 + kk);
    }
    if constexpr (AMODE == 0) {
      #pragma unroll
      for (int i = 0; i < ACPT; ++i){
        int ci = i * NT + tid;
        int row = ci >> 2, s = ci & 3;
        const float* src = Af + (size_t)(m0 + row) * lda + k0 + s * 8;
        areg[2*i]   = *(const uint4*)(src);
        areg[2*i+1] = *(const uint4*)(src + 4);
      }
    } else {
      #pragma unroll
      for (int i = 0; i < ACPT; ++i){
        int ci = i * NT + tid;
        int row = ci >> 3, slot = ci & 7;
        const unsigned short* src; int kk;
        if constexpr (SPLIT) { src = (slot < 4) ? Ahi : Alo; kk = (slot & 3) * 8; }
        else                 { src = Ahi;                    kk = slot * 8; }
        areg[i] = *(const uint4*)(src + (size_t)(m0 + row) * lda + k0 + kk);
      }
    }
  };

  auto stage_store = [&](int buf){
    char* la = smem + buf * BUF;
    char* lb = la + BM * 128;
    #pragma unroll
    for (int i = 0; i < BCPT; ++i){
      int ci = i * NT + tid;
      int row = ci >> 3, slot = ci & 7;
      *(uint4*)(lb + lofs(BN, slot, row)) = breg[i];
    }
    if constexpr (AMODE == 0) {
      #pragma unroll
      for (int i = 0; i < ACPT; ++i){
        int ci = i * NT + tid;
        int row = ci >> 2, s = ci & 3;
        const float* f0 = (const float*)&areg[2*i];
        const float* f1 = (const float*)&areg[2*i+1];
        unsigned short h[8], l[8];
        #pragma unroll
        for (int j = 0; j < 4; ++j){
          float v0 = f0[j], v1 = f1[j];
          h[j]   = f2bf(v0); l[j]   = f2bf(v0 - bf2f(h[j]));
          h[4+j] = f2bf(v1); l[4+j] = f2bf(v1 - bf2f(h[4+j]));
        }
        uint4 hv, lv;
        hv.x = pack2(h[0],h[1]); hv.y = pack2(h[2],h[3]);
        hv.z = pack2(h[4],h[5]); hv.w = pack2(h[6],h[7]);
        lv.x = pack2(l[0],l[1]); lv.y = pack2(l[2],l[3]);
        lv.z = pack2(l[4],l[5]); lv.w = pack2(l[6],l[7]);
        *(uint4*)(la + lofs(BM, s,     row)) = hv;
        *(uint4*)(la + lofs(BM, s + 4, row)) = lv;
      }
    } else {
      #pragma unroll
      for (int i = 0; i < ACPT; ++i){
        int ci = i * NT + tid;
        int row = ci >> 3, slot = ci & 7;
        *(uint4*)(la + lofs(BM, slot, row)) = areg[i];
      }
    }
  };

  const int lane = tid & 63;
  const int wv = tid >> 6;
  const int wm = wv / NWN, wn = wv % NWN;
  const int fr = lane & 15;
  const int fk = lane >> 4;     // 0..3

  facc4 acc[4][4];
  #pragma unroll
  for (int a = 0; a < 4; ++a)
    #pragma unroll
    for (int b = 0; b < 4; ++b)
      acc[a][b] = (facc4){0.f, 0.f, 0.f, 0.f};

  auto compute = [&](int buf){
    const char* la = smem + buf * BUF;
    const char* lb = la + BM * 128;
    #pragma unroll
    for (int kk = 0; kk < (SPLIT ? 1 : 2); ++kk){
      bfrag ah[4], al[4], bh[4], bl[4];
      #pragma unroll
      for (int mi = 0; mi < 4; ++mi){
        int row = wm*64 + mi*16 + fr;
        int p = SPLIT ? fk : (kk*4 + fk);
        ah[mi] = *(const bfrag*)(la + lofs(BM, p, row));
        if constexpr (SPLIT)
          al[mi] = *(const bfrag*)(la + lofs(BM, fk + 4, row));
      }
      #pragma unroll
      for (int ni = 0; ni < 4; ++ni){
        int row = wn*64 + ni*16 + fr;
        int p = SPLIT ? fk : (kk*4 + fk);
        bh[ni] = *(const bfrag*)(lb + lofs(BN, p, row));
        if constexpr (SPLIT)
          bl[ni] = *(const bfrag*)(lb + lofs(BN, fk + 4, row));
      }
      #pragma unroll
      for (int mi = 0; mi < 4; ++mi)
        #pragma unroll
        for (int ni = 0; ni < 4; ++ni){
          acc[mi][ni] = __builtin_amdgcn_mfma_f32_16x16x32_bf16(ah[mi], bh[ni], acc[mi][ni], 0, 0, 0);
          if constexpr (SPLIT){
            acc[mi][ni] = __builtin_amdgcn_mfma_f32_16x16x32_bf16(ah[mi], bl[ni], acc[mi][ni], 0, 0, 0);
            acc[mi][ni] = __builtin_amdgcn_mfma_f32_16x16x32_bf16(al[mi], bh[ni], acc[mi][ni], 0, 0, 0);
          }
        }
    }
  };

  const int NTILES = K / BK;
  stage_load(0);
  stage_store(0);
  __syncthreads();
  for (int kt = 0; kt < NTILES; ++kt){
    int cur = kt & 1;
    if (kt + 1 < NTILES) stage_load(kt + 1);
    compute(cur);
    if (kt + 1 < NTILES) stage_store(cur ^ 1);
    __syncthreads();
  }

  #pragma unroll
  for (int mi = 0; mi < 4; ++mi)
    #pragma unroll
    for (int ni = 0; ni < 4; ++ni)
      #pragma unroll
      for (int j = 0; j < 4; ++j){
        int row = m0 + wm*64 + mi*16 + (lane >> 4)*4 + j;
        int col = n0 + wn*64 + ni*16 + (lane & 15);
        float v = acc[mi][ni][j];
        if constexpr (CMODE == 0){
          ((float*)C)[(size_t)z * (size_t)cbstr + (size_t)row * ldc + col] = v;
        } else {
          unsigned short* o = (unsigned short*)C;
          unsigned short h = f2bf(v);
          o[(size_t)row * 2048 + col]        = h;
          o[(size_t)row * 2048 + 1024 + col] = f2bf(v - bf2f(h));
        }
      }
}

// W[e][n] f32  ->  Wt_hi/Wt_lo[n][e] bf16 split
__global__ __launch_bounds__(256)
void wt_kernel(const float* __restrict__ W, unsigned short* __restrict__ Whi,
               unsigned short* __restrict__ Wlo)
{
  __shared__ float tile[64][65];
  const int e0 = blockIdx.x * 64, n0 = blockIdx.y * 64;
  const int t = threadIdx.x;
  const int r = t >> 2, cq = t & 3;
  #pragma unroll
  for (int i = 0; i < 4; ++i){
    float4 f = *(const float4*)(W + (size_t)(e0 + r) * 1024 + n0 + cq*16 + i*4);
    tile[r][cq*16 + i*4 + 0] = f.x;
    tile[r][cq*16 + i*4 + 1] = f.y;
    tile[r][cq*16 + i*4 + 2] = f.z;
    tile[r][cq*16 + i*4 + 3] = f.w;
  }
  __syncthreads();
  unsigned short h[16], l[16];
  #pragma unroll
  for (int i = 0; i < 16; ++i){
    float v = tile[cq*16 + i][r];
    h[i] = f2bf(v);
    l[i] = f2bf(v - bf2f(h[i]));
  }
  uint4 ha, hb, la4, lb4;
  ha.x=pack2(h[0],h[1]);   ha.y=pack2(h[2],h[3]);   ha.z=pack2(h[4],h[5]);   ha.w=pack2(h[6],h[7]);
  hb.x=pack2(h[8],h[9]);   hb.y=pack2(h[10],h[11]); hb.z=pack2(h[12],h[13]); hb.w=pack2(h[14],h[15]);
  la4.x=pack2(l[0],l[1]);  la4.y=pack2(l[2],l[3]);  la4.z=pack2(l[4],l[5]);  la4.w=pack2(l[6],l[7]);
  lb4.x=pack2(l[8],l[9]);  lb4.y=pack2(l[10],l[11]);lb4.z=pack2(l[12],l[13]);lb4.w=pack2(l[14],l[15]);
  size_t o = (size_t)(n0 + r) * 1024 + e0 + cq*16;
  *(uint4*)(Whi + o)     = ha;
  *(uint4*)(Whi + o + 8) = hb;
  *(uint4*)(Wlo + o)     = la4;
  *(uint4*)(Wlo + o + 8) = lb4;
}

// k[b][kv][e] f32 -> khi/klo[b][kv][e] bf16 and kT[b][e][kv] bf16 (hi only)
__global__ __launch_bounds__(256)
void prep_kernel(const float* __restrict__ kin, unsigned short* __restrict__ khi,
                 unsigned short* __restrict__ klo, unsigned short* __restrict__ kT)
{
  __shared__ float tile[64][65];
  const int bz = blockIdx.z;
  const float* kb = kin + (size_t)bz * 2048 * 1024;
  unsigned short* khib = khi + (size_t)bz * 2048 * 1024;
  unsigned short* klob = klo + (size_t)bz * 2048 * 1024;
  unsigned short* kTb  = kT  + (size_t)bz * 1024 * 2048;
  const int kv0 = blockIdx.x * 64, e0 = blockIdx.y * 64;
  const int t = threadIdx.x;
  const int r = t >> 2, cq = t & 3;
  #pragma unroll
  for (int i = 0; i < 4; ++i){
    float4 f = *(const float4*)(kb + (size_t)(kv0 + r) * 1024 + e0 + cq*16 + i*4);
    unsigned short h0=f2bf(f.x), h1=f2bf(f.y), h2=f2bf(f.z), h3=f2bf(f.w);
    uint2 hv, lv;
    hv.x = pack2(h0, h1); hv.y = pack2(h2, h3);
    lv.x = pack2(f2bf(f.x - bf2f(h0)), f2bf(f.y - bf2f(h1)));
    lv.y = pack2(f2bf(f.z - bf2f(h2)), f2bf(f.w - bf2f(h3)));
    size_t o = (size_t)(kv0 + r) * 1024 + e0 + cq*16 + i*4;
    *(uint2*)(khib + o) = hv;
    *(uint2*)(klob + o) = lv;
    tile[r][cq*16 + i*4 + 0] = f.x;
    tile[r][cq*16 + i*4 + 1] = f.y;
    tile[r][cq*16 + i*4 + 2] = f.z;
    tile[r][cq*16 + i*4 + 3] = f.w;
  }
  __syncthreads();
  unsigned short h[16];
  #pragma unroll
  for (int i = 0; i < 16; ++i) h[i] = f2bf(tile[cq*16 + i][r]);
  uint4 va, vb;
  va.x=pack2(h[0],h[1]);  va.y=pack2(h[2],h[3]);   va.z=pack2(h[4],h[5]);   va.w=pack2(h[6],h[7]);
  vb.x=pack2(h[8],h[9]);  vb.y=pack2(h[10],h[11]); vb.z=pack2(h[12],h[13]); vb.w=pack2(h[14],h[15]);
  size_t o = (size_t)(e0 + r) * 2048 + kv0 + cq*16;
  *(uint4*)(kTb + o)     = va;
  *(uint4*)(kTb + o + 8) = vb;
}

// exact row softmax over 2048 f32, then * mask, -> bf16
__global__ __launch_bounds__(256)
void softmax_kernel(const float* __restrict__ S, const int* __restrict__ mask,
                    unsigned short* __restrict__ P)
{
  const int row = blockIdx.x;
  const float* s = S + (size_t)row * 2048;
  const int* mk = mask + (size_t)row * 2048;
  unsigned short* p = P + (size_t)row * 2048;
  const int t = threadIdx.x;
  float4 v0 = ((const float4*)s)[t];
  float4 v1 = ((const float4*)s)[t + 256];
  float m = fmaxf(fmaxf(fmaxf(v0.x, v0.y), fmaxf(v0.z, v0.w)),
                  fmaxf(fmaxf(v1.x, v1.y), fmaxf(v1.z, v1.w)));
  #pragma unroll
  for (int off = 32; off > 0; off >>= 1) m = fmaxf(m, __shfl_xor(m, off));
  __shared__ float rmax[4], rsum[4];
  const int wid = t >> 6;
  if ((t & 63) == 0) rmax[wid] = m;
  __syncthreads();
  m = fmaxf(fmaxf(rmax[0], rmax[1]), fmaxf(rmax[2], rmax[3]));
  float e0 = __expf(v0.x - m), e1 = __expf(v0.y - m), e2 = __expf(v0.z - m), e3 = __expf(v0.w - m);
  float e4 = __expf(v1.x - m), e5 = __expf(v1.y - m), e6 = __expf(v1.z - m), e7 = __expf(v1.w - m);
  float ssum = ((e0 + e1) + (e2 + e3)) + ((e4 + e5) + (e6 + e7));
  #pragma unroll
  for (int off = 32; off > 0; off >>= 1) ssum += __shfl_xor(ssum, off);
  if ((t & 63) == 0) rsum[wid] = ssum;
  __syncthreads();
  float inv = 1.f / (rsum[0] + rsum[1] + rsum[2] + rsum[3]);
  int4 m0 = ((const int4*)mk)[t];
  int4 m1 = ((const int4*)mk)[t + 256];
  ushort4 o0, o1;
  o0.x = f2bf(e0 * inv * (float)m0.x);
  o0.y = f2bf(e1 * inv * (float)m0.y);
  o0.z = f2bf(e2 * inv * (float)m0.z);
  o0.w = f2bf(e3 * inv * (float)m0.w);
  o1.x = f2bf(e4 * inv * (float)m1.x);
  o1.y = f2bf(e5 * inv * (float)m1.y);
  o1.z = f2bf(e6 * inv * (float)m1.z);
  o1.w = f2bf(e7 * inv * (float)m1.w);
  ((ushort4*)p)[t]       = o0;
  ((ushort4*)p)[t + 256] = o1;
}

extern "C" void kernel_launch(void* const* d_in, const int* in_sizes, int n_in,
                              void* d_out, int out_size, void* d_ws, size_t ws_size,
                              hipStream_t stream)
{
  (void)in_sizes; (void)n_in; (void)out_size;
  const float* kin  = (const float*)d_in[0];
  const float* qin  = (const float*)d_in[1];
  const float* Win  = (const float*)d_in[2];
  const int*   mask = (const int*)d_in[3];

  // ws layout: Wt_hi (2MB) | Wt_lo (2MB) | per-chunk { khi | klo | kT | S | P }
  unsigned short* Wt_hi = (unsigned short*)d_ws;
  unsigned short* Wt_lo = Wt_hi + 1024 * 1024;
  char* cbase = (char*)d_ws + (4ll << 20);

  int bpc = 1;  // batches per chunk (36 MB each + 4 MB fixed)
  {
    const size_t per_b = (size_t)2048*1024*2*2 + (size_t)1024*2048*2
                       + (size_t)2048*2048*4 + (size_t)2048*2048*2;
    const int cands[5] = {16, 8, 4, 2, 1};
    for (int i = 0; i < 5; ++i){
      size_t need = (4ull << 20) + (size_t)cands[i] * per_b;
      if (need <= ws_size){ bpc = cands[i]; break; }
    }
  }
  unsigned short* khi = (unsigned short*)cbase;
  unsigned short* klo = khi + (size_t)bpc * 2048 * 1024;
  unsigned short* kT  = klo + (size_t)bpc * 2048 * 1024;
  float*          Sb  = (float*)(kT + (size_t)bpc * 1024 * 2048);
  unsigned short* Pb  = (unsigned short*)(Sb + (size_t)bpc * 2048 * 2048);

  // K0: W transpose+split
  wt_kernel<<<dim3(16, 16, 1), 256, 0, stream>>>(Win, Wt_hi, Wt_lo);

  // K1: qw = q @ W  (f32-split 3-pass), -> d_out as interleaved hi|lo bf16 rows
  gemm_kernel<0, 128, 128, 4, 1><<<dim3(32768/128, 1024/128, 1), 256, 0, stream>>>(
      qin, nullptr, Wt_hi, Wt_lo, d_out,
      1024, 1024, 0, 1024, 0, 0, 0);

  for (int cb = 0; cb < 16; cb += bpc){
    prep_kernel<<<dim3(32, 16, bpc), 256, 0, stream>>>(
        kin + (size_t)cb * 2048 * 1024, khi, klo, kT);

    // K2: S = qw @ k^T (pre-split bf16 3-pass), batched
    const unsigned short* qw = (const unsigned short*)d_out + (size_t)cb * 2048 * 2048;
    gemm_kernel<1, 128, 128, 4, 0><<<dim3(2048/128, 2048/128, bpc), 256, 0, stream>>>(
        qw, qw + 1024, khi, klo, Sb,
        2048, 1024, 2048, 1024,
        (long)2048 * 2048, (long)2048 * 1024, (long)2048 * 2048);

    // K3: row softmax * mask -> P (bf16)
    softmax_kernel<<<dim3(bpc * 2048, 1, 1), 256, 0, stream>>>(
        Sb, mask + (size_t)cb * 2048 * 2048, Pb);

    // K4: O = P @ k (plain bf16), overwrites this chunk's qw rows in d_out
    gemm_kernel<2, 128, 128, 4, 0><<<dim3(2048/128, 1024/128, bpc), 256, 0, stream>>>(
        Pb, nullptr, kT, nullptr, (float*)d_out + (size_t)cb * 2048 * 1024,
        2048, 2048, 1024, 2048,
        (long)2048 * 2048, (long)1024 * 2048, (long)2048 * 1024);
  }
}

// Round 5
// 1286.541 us; speedup vs baseline: 1.3061x; 1.3061x over previous
//
#include <hip/hip_runtime.h>
#include <stdint.h>

typedef short bfrag __attribute__((ext_vector_type(8)));   // 8 bf16 (4 VGPR)
typedef float facc4 __attribute__((ext_vector_type(4)));   // MFMA accumulator
typedef unsigned int u32;

__device__ __forceinline__ unsigned short f2bf(float x){
  union { float f; uint32_t u; } v; v.f = x;
  uint32_t r = v.u + 0x7FFFu + ((v.u >> 16) & 1u);   // RNE
  return (unsigned short)(r >> 16);
}
__device__ __forceinline__ float bf2f(unsigned short h){
  union { uint32_t u; float f; } v; v.u = ((uint32_t)h) << 16; return v.f;
}
__device__ __forceinline__ uint32_t pack2(unsigned short a, unsigned short b){
  return (uint32_t)a | ((uint32_t)b << 16);
}

__device__ __forceinline__ void gload_lds16(const void* g, void* l){
  __builtin_amdgcn_global_load_lds(
      (const __attribute__((address_space(1))) void*)g,
      (__attribute__((address_space(3))) void*)l, 16, 0, 0);
}

// ---------------------------------------------------------------------------
// m97-style plain-bf16 GEMM: 128x128 tile, 4 waves, BK=32, double-buffered
// 32KB LDS, global_load_lds width-16 staging (linear LDS dest, source
// pre-swizzled by slot^(row&3); ds_read applies the same XOR -> 2-way max).
// A: [M][K] bf16 row-major (lda), B: [N][K] bf16 row-major (ldb).
// OUT: 0 = f32 C (ldc, batched by cbstr). 1 = qwcat: per element writes
//      hi at col, hi at col+1024, lo at col+2048, row stride 3072.
// ---------------------------------------------------------------------------
template<int OUT>
__global__ __launch_bounds__(256)
void gemm97(const unsigned short* __restrict__ A,
            const unsigned short* __restrict__ B,
            void* __restrict__ C,
            int K, int lda, int ldb, int ldc,
            long abstr, long bbstr, long cbstr)
{
  __shared__ __align__(16) unsigned short lds[2][2][128 * 32];  // 32 KB

  const int tid  = threadIdx.x;
  const int lane = tid & 63;
  const int wv   = tid >> 6;
  const int z    = blockIdx.z;
  const int m0   = blockIdx.x * 128;
  const int n0   = blockIdx.y * 128;

  const unsigned short* Ab = A + (size_t)z * (size_t)abstr;
  const unsigned short* Bb = B + (size_t)z * (size_t)bbstr;

  // staging geometry: each 1KB segment = 16 rows x 64B; lane l covers
  // (row = seg*16 + l>>2, slot = l&3); global source pre-swizzled so that
  // LDS[row][slot] holds k-chunk (slot ^ (row&3)).
  const int srow  = lane >> 2;                    // 0..15
  const int sslot = (lane & 3) ^ (srow & 3);      // pre-swizzled k-chunk
  const int seg0  = wv * 2;                       // waves 0-3 -> segs 0..7

  auto stage = [&](int buf, int kt){
    const int k0 = kt * 32;
    #pragma unroll
    for (int i = 0; i < 2; ++i){
      const int seg = seg0 + i;
      const int row = seg * 16 + srow;
      gload_lds16(Ab + (size_t)(m0 + row) * lda + k0 + sslot * 8,
                  &lds[buf][0][seg * 512]);
      gload_lds16(Bb + (size_t)(n0 + row) * ldb + k0 + sslot * 8,
                  &lds[buf][1][seg * 512]);
    }
  };

  const int fr = lane & 15;
  const int fk = lane >> 4;         // 0..3
  const int wm = wv >> 1, wn = wv & 1;   // 2x2 waves, 64x64 each

  facc4 acc[4][4];
  #pragma unroll
  for (int a = 0; a < 4; ++a)
    #pragma unroll
    for (int b = 0; b < 4; ++b)
      acc[a][b] = (facc4){0.f, 0.f, 0.f, 0.f};

  auto compute = [&](int buf){
    bfrag av[4], bv[4];
    #pragma unroll
    for (int mi = 0; mi < 4; ++mi){
      int row = wm * 64 + mi * 16 + fr;
      av[mi] = *(const bfrag*)&lds[buf][0][row * 32 + ((fk ^ (row & 3)) * 8)];
    }
    #pragma unroll
    for (int ni = 0; ni < 4; ++ni){
      int row = wn * 64 + ni * 16 + fr;
      bv[ni] = *(const bfrag*)&lds[buf][1][row * 32 + ((fk ^ (row & 3)) * 8)];
    }
    #pragma unroll
    for (int mi = 0; mi < 4; ++mi)
      #pragma unroll
      for (int ni = 0; ni < 4; ++ni)
        acc[mi][ni] = __builtin_amdgcn_mfma_f32_16x16x32_bf16(av[mi], bv[ni], acc[mi][ni], 0, 0, 0);
  };

  const int NT = K / 32;
  stage(0, 0);
  asm volatile("s_waitcnt vmcnt(0)" ::: "memory");
  __syncthreads();
  for (int kt = 0; kt < NT; ++kt){
    const int cur = kt & 1;
    if (kt + 1 < NT) stage(cur ^ 1, kt + 1);
    compute(cur);
    asm volatile("s_waitcnt vmcnt(0)" ::: "memory");
    __syncthreads();
  }

  #pragma unroll
  for (int mi = 0; mi < 4; ++mi)
    #pragma unroll
    for (int ni = 0; ni < 4; ++ni)
      #pragma unroll
      for (int j = 0; j < 4; ++j){
        int row = m0 + wm * 64 + mi * 16 + fk * 4 + j;
        int col = n0 + wn * 64 + ni * 16 + fr;
        float v = acc[mi][ni][j];
        if constexpr (OUT == 0){
          ((float*)C)[(size_t)z * (size_t)cbstr + (size_t)row * ldc + col] = v;
        } else {
          unsigned short* o = (unsigned short*)C;
          unsigned short h = f2bf(v);
          size_t base = (size_t)row * 3072 + col;
          o[base]        = h;
          o[base + 1024] = h;
          o[base + 2048] = f2bf(v - bf2f(h));
        }
      }
}

// W[e][n] f32 -> Wtcat[n][3072] = [Wt_h | Wt_l | Wt_h] bf16
__global__ __launch_bounds__(256)
void wtcat_kernel(const float* __restrict__ W, unsigned short* __restrict__ Wcat)
{
  __shared__ float tile[64][65];
  const int e0 = blockIdx.x * 64, n0 = blockIdx.y * 64;
  const int t = threadIdx.x;
  const int r = t >> 2, cq = t & 3;
  #pragma unroll
  for (int i = 0; i < 4; ++i){
    float4 f = *(const float4*)(W + (size_t)(e0 + r) * 1024 + n0 + cq*16 + i*4);
    tile[r][cq*16 + i*4 + 0] = f.x;
    tile[r][cq*16 + i*4 + 1] = f.y;
    tile[r][cq*16 + i*4 + 2] = f.z;
    tile[r][cq*16 + i*4 + 3] = f.w;
  }
  __syncthreads();
  unsigned short h[16], l[16];
  #pragma unroll
  for (int i = 0; i < 16; ++i){
    float v = tile[cq*16 + i][r];
    h[i] = f2bf(v);
    l[i] = f2bf(v - bf2f(h[i]));
  }
  uint4 ha, hb, la4, lb4;
  ha.x=pack2(h[0],h[1]);   ha.y=pack2(h[2],h[3]);   ha.z=pack2(h[4],h[5]);   ha.w=pack2(h[6],h[7]);
  hb.x=pack2(h[8],h[9]);   hb.y=pack2(h[10],h[11]); hb.z=pack2(h[12],h[13]); hb.w=pack2(h[14],h[15]);
  la4.x=pack2(l[0],l[1]);  la4.y=pack2(l[2],l[3]);  la4.z=pack2(l[4],l[5]);  la4.w=pack2(l[6],l[7]);
  lb4.x=pack2(l[8],l[9]);  lb4.y=pack2(l[10],l[11]);lb4.z=pack2(l[12],l[13]);lb4.w=pack2(l[14],l[15]);
  size_t o = (size_t)(n0 + r) * 3072 + e0 + cq*16;
  *(uint4*)(Wcat + o)          = ha;
  *(uint4*)(Wcat + o + 8)      = hb;
  *(uint4*)(Wcat + o + 1024)   = la4;
  *(uint4*)(Wcat + o + 1032)   = lb4;
  *(uint4*)(Wcat + o + 2048)   = ha;
  *(uint4*)(Wcat + o + 2056)   = hb;
}

// q rows f32 [R][1024] -> qcat[R][3072] = [q_h | q_h | q_l]
__global__ __launch_bounds__(256)
void qprep_kernel(const float* __restrict__ q, unsigned short* __restrict__ qcat)
{
  const int gid = blockIdx.x * 256 + threadIdx.x;
  const int row = gid >> 7;
  const int c8  = (gid & 127) * 8;
  const float* src = q + (size_t)row * 1024 + c8;
  float4 f0 = *(const float4*)src;
  float4 f1 = *(const float4*)(src + 4);
  float vs[8] = {f0.x, f0.y, f0.z, f0.w, f1.x, f1.y, f1.z, f1.w};
  unsigned short h[8], l[8];
  #pragma unroll
  for (int i = 0; i < 8; ++i){ h[i] = f2bf(vs[i]); l[i] = f2bf(vs[i] - bf2f(h[i])); }
  uint4 hv, lv;
  hv.x=pack2(h[0],h[1]); hv.y=pack2(h[2],h[3]); hv.z=pack2(h[4],h[5]); hv.w=pack2(h[6],h[7]);
  lv.x=pack2(l[0],l[1]); lv.y=pack2(l[2],l[3]); lv.z=pack2(l[4],l[5]); lv.w=pack2(l[6],l[7]);
  size_t o = (size_t)row * 3072 + c8;
  *(uint4*)(qcat + o)        = hv;
  *(uint4*)(qcat + o + 1024) = hv;
  *(uint4*)(qcat + o + 2048) = lv;
}

// k[b][kv][e] f32 -> kcat[b][kv][3072] = [k_h | k_l | k_h] and kT[b][e][kv] (hi)
__global__ __launch_bounds__(256)
void kprep_kernel(const float* __restrict__ kin, unsigned short* __restrict__ kcat,
                  unsigned short* __restrict__ kT)
{
  __shared__ float tile[64][65];
  const int bz = blockIdx.z;
  const float* kb = kin + (size_t)bz * 2048 * 1024;
  unsigned short* kcb = kcat + (size_t)bz * 2048 * 3072;
  unsigned short* kTb = kT  + (size_t)bz * 1024 * 2048;
  const int kv0 = blockIdx.x * 64, e0 = blockIdx.y * 64;
  const int t = threadIdx.x;
  const int r = t >> 2, cq = t & 3;
  #pragma unroll
  for (int i = 0; i < 4; ++i){
    float4 f = *(const float4*)(kb + (size_t)(kv0 + r) * 1024 + e0 + cq*16 + i*4);
    unsigned short h0=f2bf(f.x), h1=f2bf(f.y), h2=f2bf(f.z), h3=f2bf(f.w);
    uint2 hv, lv;
    hv.x = pack2(h0, h1); hv.y = pack2(h2, h3);
    lv.x = pack2(f2bf(f.x - bf2f(h0)), f2bf(f.y - bf2f(h1)));
    lv.y = pack2(f2bf(f.z - bf2f(h2)), f2bf(f.w - bf2f(h3)));
    size_t o = (size_t)(kv0 + r) * 3072 + e0 + cq*16 + i*4;
    *(uint2*)(kcb + o)        = hv;
    *(uint2*)(kcb + o + 1024) = lv;
    *(uint2*)(kcb + o + 2048) = hv;
    tile[r][cq*16 + i*4 + 0] = f.x;
    tile[r][cq*16 + i*4 + 1] = f.y;
    tile[r][cq*16 + i*4 + 2] = f.z;
    tile[r][cq*16 + i*4 + 3] = f.w;
  }
  __syncthreads();
  unsigned short h[16];
  #pragma unroll
  for (int i = 0; i < 16; ++i) h[i] = f2bf(tile[cq*16 + i][r]);
  uint4 va, vb;
  va.x=pack2(h[0],h[1]);  va.y=pack2(h[2],h[3]);   va.z=pack2(h[4],h[5]);   va.w=pack2(h[6],h[7]);
  vb.x=pack2(h[8],h[9]);  vb.y=pack2(h[10],h[11]); vb.z=pack2(h[12],h[13]); vb.w=pack2(h[14],h[15]);
  size_t o = (size_t)(e0 + r) * 2048 + kv0 + cq*16;
  *(uint4*)(kTb + o)     = va;
  *(uint4*)(kTb + o + 8) = vb;
}

// exact row softmax over 2048 f32, then * mask, -> bf16
__global__ __launch_bounds__(256)
void softmax_kernel(const float* __restrict__ S, const int* __restrict__ mask,
                    unsigned short* __restrict__ P)
{
  const int row = blockIdx.x;
  const float* s = S + (size_t)row * 2048;
  const int* mk = mask + (size_t)row * 2048;
  unsigned short* p = P + (size_t)row * 2048;
  const int t = threadIdx.x;
  float4 v0 = ((const float4*)s)[t];
  float4 v1 = ((const float4*)s)[t + 256];
  float m = fmaxf(fmaxf(fmaxf(v0.x, v0.y), fmaxf(v0.z, v0.w)),
                  fmaxf(fmaxf(v1.x, v1.y), fmaxf(v1.z, v1.w)));
  #pragma unroll
  for (int off = 32; off > 0; off >>= 1) m = fmaxf(m, __shfl_xor(m, off));
  __shared__ float rmax[4], rsum[4];
  const int wid = t >> 6;
  if ((t & 63) == 0) rmax[wid] = m;
  __syncthreads();
  m = fmaxf(fmaxf(rmax[0], rmax[1]), fmaxf(rmax[2], rmax[3]));
  float e0 = __expf(v0.x - m), e1 = __expf(v0.y - m), e2 = __expf(v0.z - m), e3 = __expf(v0.w - m);
  float e4 = __expf(v1.x - m), e5 = __expf(v1.y - m), e6 = __expf(v1.z - m), e7 = __expf(v1.w - m);
  float ssum = ((e0 + e1) + (e2 + e3)) + ((e4 + e5) + (e6 + e7));
  #pragma unroll
  for (int off = 32; off > 0; off >>= 1) ssum += __shfl_xor(ssum, off);
  if ((t & 63) == 0) rsum[wid] = ssum;
  __syncthreads();
  float inv = 1.f / (rsum[0] + rsum[1] + rsum[2] + rsum[3]);
  int4 m0 = ((const int4*)mk)[t];
  int4 m1 = ((const int4*)mk)[t + 256];
  ushort4 o0, o1;
  o0.x = f2bf(e0 * inv * (float)m0.x);
  o0.y = f2bf(e1 * inv * (float)m0.y);
  o0.z = f2bf(e2 * inv * (float)m0.z);
  o0.w = f2bf(e3 * inv * (float)m0.w);
  o1.x = f2bf(e4 * inv * (float)m1.x);
  o1.y = f2bf(e5 * inv * (float)m1.y);
  o1.z = f2bf(e6 * inv * (float)m1.z);
  o1.w = f2bf(e7 * inv * (float)m1.w);
  ((ushort4*)p)[t]       = o0;
  ((ushort4*)p)[t + 256] = o1;
}

extern "C" void kernel_launch(void* const* d_in, const int* in_sizes, int n_in,
                              void* d_out, int out_size, void* d_ws, size_t ws_size,
                              hipStream_t stream)
{
  (void)in_sizes; (void)n_in; (void)out_size;
  const float* kin  = (const float*)d_in[0];
  const float* qin  = (const float*)d_in[1];
  const float* Win  = (const float*)d_in[2];
  const int*   mask = (const int*)d_in[3];

  // ws: Wtcat (6MB) | per-chunk { qcat | qwcat | kcat | kT | S | P }
  int bpc = 1;
  {
    const size_t per_b = (size_t)2048*3072*2*3 + (size_t)1024*2048*2
                       + (size_t)2048*2048*4 + (size_t)2048*2048*2;   // 67.1 MB
    const size_t fixed = (size_t)1024*3072*2;
    const int cands[5] = {16, 8, 4, 2, 1};
    for (int i = 0; i < 5; ++i){
      if (fixed + (size_t)cands[i] * per_b <= ws_size){ bpc = cands[i]; break; }
    }
  }
  unsigned short* Wtcat = (unsigned short*)d_ws;
  unsigned short* qcat  = Wtcat + (size_t)1024*3072;
  unsigned short* qwcat = qcat  + (size_t)bpc*2048*3072;
  unsigned short* kcat  = qwcat + (size_t)bpc*2048*3072;
  unsigned short* kT    = kcat  + (size_t)bpc*2048*3072;
  float*          Sb    = (float*)(kT + (size_t)bpc*1024*2048);
  unsigned short* Pb    = (unsigned short*)(Sb + (size_t)bpc*2048*2048);

  wtcat_kernel<<<dim3(16, 16, 1), 256, 0, stream>>>(Win, Wtcat);

  for (int cb = 0; cb < 16; cb += bpc){
    // q rows for this chunk -> split/cat
    qprep_kernel<<<dim3(bpc * 1024, 1, 1), 256, 0, stream>>>(
        qin + (size_t)cb * 2048 * 1024, qcat);

    // K1: qw = qcat @ Wtcat^T (K=3072) -> qwcat (split-interleaved, K=3072)
    gemm97<1><<<dim3(bpc * 16, 8, 1), 256, 0, stream>>>(
        qcat, Wtcat, qwcat, 3072, 3072, 3072, 0, 0, 0, 0);

    kprep_kernel<<<dim3(32, 16, bpc), 256, 0, stream>>>(
        kin + (size_t)cb * 2048 * 1024, kcat, kT);

    // K2: S = qwcat @ kcat^T (K=3072), batched
    gemm97<0><<<dim3(16, 16, bpc), 256, 0, stream>>>(
        qwcat, kcat, Sb, 3072, 3072, 3072, 2048,
        (long)2048 * 3072, (long)2048 * 3072, (long)2048 * 2048);

    // K3: row softmax * mask -> P (bf16)
    softmax_kernel<<<dim3(bpc * 2048, 1, 1), 256, 0, stream>>>(
        Sb, mask + (size_t)cb * 2048 * 2048, Pb);

    // K4: O = P @ kT^T (K=2048), batched -> d_out
    gemm97<0><<<dim3(16, 8, bpc), 256, 0, stream>>>(
        Pb, kT, (float*)d_out + (size_t)cb * 2048 * 1024, 2048, 2048, 2048, 1024,
        (long)2048 * 2048, (long)1024 * 2048, (long)2048 * 1024);
  }
}

// Round 6
// 1142.771 us; speedup vs baseline: 1.4704x; 1.1258x over previous
//
#include <hip/hip_runtime.h>
#include <stdint.h>

typedef short bfrag __attribute__((ext_vector_type(8)));   // 8 bf16 (4 VGPR)
typedef float facc4 __attribute__((ext_vector_type(4)));   // MFMA accumulator

__device__ __forceinline__ unsigned short f2bf(float x){
  union { float f; uint32_t u; } v; v.f = x;
  uint32_t r = v.u + 0x7FFFu + ((v.u >> 16) & 1u);   // RNE
  return (unsigned short)(r >> 16);
}
__device__ __forceinline__ float bf2f(unsigned short h){
  union { uint32_t u; float f; } v; v.u = ((uint32_t)h) << 16; return v.f;
}
__device__ __forceinline__ uint32_t pack2(unsigned short a, unsigned short b){
  return (uint32_t)a | ((uint32_t)b << 16);
}

__device__ __forceinline__ void gload_lds16(const void* g, void* l){
  __builtin_amdgcn_global_load_lds(
      (const __attribute__((address_space(1))) void*)g,
      (__attribute__((address_space(3))) void*)l, 16, 0, 0);
}

// ---------------------------------------------------------------------------
// 256x256 deep-pipelined bf16 GEMM, 8 waves (2M x 4N), BK=64, 128KB LDS dbuf.
//
// LDS is FRAGMENT-MAJOR: tile = 32 fragments of 1KB; fragment f = (rg, ks)
// holds rows rg*16..+15, k ks*32..+31 in exact MFMA lane order
// (lane = fk*16+fr -> elem [row rg*16+fr][k ks*32+fk*8 .. +7]).
// DMA write (uniform base + lane*16) and ds_read_b128 (base + lane*16) are
// both contiguous 1KB -> zero bank conflicts by construction (rule #21:
// source permutation == read permutation == identity in lane order).
//
// Pipeline (T4, counted vmcnt, never 0 in steady state):
//   stage(0,0); stage(1,1)                       // 16 loads/thread in flight
//   for t: wait vmcnt(8)  [tile t complete]      // t+1's 8 stay in flight
//          barrier; compute(buf t&1);
//          lgkmcnt(0); barrier;                  // all reads of buf done
//          stage(buf t&1, t+2)                   // overwrite dead buffer
//
// REMAP=1: A,B are [hi(1024)|lo(1024)] bf16, NT=48 encodes the 3-pass
// split-product  Ah*Bh + Ah*Bl + Al*Bh  via akt=(kt<16?kt:kt-16),
// bkt=(kt<32?kt:kt-32).  REMAP=0: plain K, NT=K/64.
// OUT: 0 = f32 C (ldc, cbstr).  1 = split write: hi at [row*2048+col],
//      lo at [row*2048+1024+col].
// ---------------------------------------------------------------------------
template<int REMAP, int OUT>
__global__ __launch_bounds__(512, 2)
void gemm256(const unsigned short* __restrict__ A,
             const unsigned short* __restrict__ B,
             void* __restrict__ C,
             int NT, int lda, int ldb, int ldc,
             long abstr, long bbstr, long cbstr)
{
  __shared__ __align__(16) unsigned short lds[2][2][16384];   // 128 KB

  const int tid  = threadIdx.x;
  const int lane = tid & 63;
  const int wv   = tid >> 6;          // 0..7
  const int wm   = wv >> 2;           // 0..1  -> 128 rows
  const int wn   = wv & 3;            // 0..3  -> 64 cols
  const int z    = blockIdx.z;
  const int m0   = blockIdx.x * 256;
  const int n0   = blockIdx.y * 256;

  const unsigned short* Ab = A + (size_t)z * (size_t)abstr;
  const unsigned short* Bb = B + (size_t)z * (size_t)bbstr;

  const int fr  = lane & 15;
  const int fkc = lane >> 4;          // 0..3

  auto stage = [&](int buf, int kt){
    int akt = kt, bkt = kt;
    if (REMAP){ akt = (kt < 16) ? kt : kt - 16; bkt = (kt < 32) ? kt : kt - 32; }
    const int k0a = akt * 64, k0b = bkt * 64;
    #pragma unroll
    for (int j = 0; j < 4; ++j){
      const int f  = j * 8 + wv;      // fragment 0..31 (uniform per wave)
      const int rg = f >> 1, ks = f & 1;
      gload_lds16(Ab + (size_t)(m0 + rg * 16 + fr) * lda + k0a + ks * 32 + fkc * 8,
                  &lds[buf][0][f * 512]);
      gload_lds16(Bb + (size_t)(n0 + rg * 16 + fr) * ldb + k0b + ks * 32 + fkc * 8,
                  &lds[buf][1][f * 512]);
    }
  };

  facc4 acc[8][4];
  #pragma unroll
  for (int a = 0; a < 8; ++a)
    #pragma unroll
    for (int b = 0; b < 4; ++b)
      acc[a][b] = (facc4){0.f, 0.f, 0.f, 0.f};

  auto compute = [&](int buf){
    const unsigned short* la = lds[buf][0];
    const unsigned short* lb = lds[buf][1];
    bfrag bv[4][2];
    #pragma unroll
    for (int ni = 0; ni < 4; ++ni)
      #pragma unroll
      for (int ks = 0; ks < 2; ++ks)
        bv[ni][ks] = *(const bfrag*)(lb + ((((wn * 4 + ni) * 2 + ks)) << 9) + lane * 8);
    #pragma unroll
    for (int mi = 0; mi < 8; ++mi){
      const int fa = (wm * 8 + mi) * 2;
      bfrag a0 = *(const bfrag*)(la + (fa << 9) + lane * 8);
      bfrag a1 = *(const bfrag*)(la + ((fa + 1) << 9) + lane * 8);
      __builtin_amdgcn_s_setprio(1);
      #pragma unroll
      for (int ni = 0; ni < 4; ++ni){
        acc[mi][ni] = __builtin_amdgcn_mfma_f32_16x16x32_bf16(a0, bv[ni][0], acc[mi][ni], 0, 0, 0);
        acc[mi][ni] = __builtin_amdgcn_mfma_f32_16x16x32_bf16(a1, bv[ni][1], acc[mi][ni], 0, 0, 0);
      }
      __builtin_amdgcn_s_setprio(0);
    }
  };

  stage(0, 0);
  stage(1, 1);
  for (int t = 0; t < NT; ++t){
    if (t + 1 < NT) asm volatile("s_waitcnt vmcnt(8)" ::: "memory");
    else            asm volatile("s_waitcnt vmcnt(0)" ::: "memory");
    asm volatile("s_barrier" ::: "memory");
    compute(t & 1);
    asm volatile("s_waitcnt lgkmcnt(0)" ::: "memory");
    asm volatile("s_barrier" ::: "memory");
    if (t + 2 < NT) stage(t & 1, t + 2);
  }

  #pragma unroll
  for (int mi = 0; mi < 8; ++mi)
    #pragma unroll
    for (int ni = 0; ni < 4; ++ni)
      #pragma unroll
      for (int j = 0; j < 4; ++j){
        const int row = m0 + wm * 128 + mi * 16 + fkc * 4 + j;
        const int col = n0 + wn * 64 + ni * 16 + fr;
        const float v = acc[mi][ni][j];
        if constexpr (OUT == 0){
          ((float*)C)[(size_t)z * (size_t)cbstr + (size_t)row * ldc + col] = v;
        } else {
          unsigned short* o = (unsigned short*)C;
          const unsigned short h = f2bf(v);
          o[(size_t)row * 2048 + col]        = h;
          o[(size_t)row * 2048 + 1024 + col] = f2bf(v - bf2f(h));
        }
      }
}

// W[e][n] f32 -> Wt[n][2048] = [Wt_h | Wt_l] bf16
__global__ __launch_bounds__(256)
void wtprep_kernel(const float* __restrict__ W, unsigned short* __restrict__ Wt)
{
  __shared__ float tile[64][65];
  const int e0 = blockIdx.x * 64, n0 = blockIdx.y * 64;
  const int t = threadIdx.x;
  const int r = t >> 2, cq = t & 3;
  #pragma unroll
  for (int i = 0; i < 4; ++i){
    float4 f = *(const float4*)(W + (size_t)(e0 + r) * 1024 + n0 + cq*16 + i*4);
    tile[r][cq*16 + i*4 + 0] = f.x;
    tile[r][cq*16 + i*4 + 1] = f.y;
    tile[r][cq*16 + i*4 + 2] = f.z;
    tile[r][cq*16 + i*4 + 3] = f.w;
  }
  __syncthreads();
  unsigned short h[16], l[16];
  #pragma unroll
  for (int i = 0; i < 16; ++i){
    float v = tile[cq*16 + i][r];
    h[i] = f2bf(v);
    l[i] = f2bf(v - bf2f(h[i]));
  }
  uint4 ha, hb, la4, lb4;
  ha.x=pack2(h[0],h[1]);   ha.y=pack2(h[2],h[3]);   ha.z=pack2(h[4],h[5]);   ha.w=pack2(h[6],h[7]);
  hb.x=pack2(h[8],h[9]);   hb.y=pack2(h[10],h[11]); hb.z=pack2(h[12],h[13]); hb.w=pack2(h[14],h[15]);
  la4.x=pack2(l[0],l[1]);  la4.y=pack2(l[2],l[3]);  la4.z=pack2(l[4],l[5]);  la4.w=pack2(l[6],l[7]);
  lb4.x=pack2(l[8],l[9]);  lb4.y=pack2(l[10],l[11]);lb4.z=pack2(l[12],l[13]);lb4.w=pack2(l[14],l[15]);
  size_t o = (size_t)(n0 + r) * 2048 + e0 + cq*16;
  *(uint4*)(Wt + o)          = ha;
  *(uint4*)(Wt + o + 8)      = hb;
  *(uint4*)(Wt + o + 1024)   = la4;
  *(uint4*)(Wt + o + 1032)   = lb4;
}

// q rows f32 [R][1024] -> qsplit[R][2048] = [q_h | q_l]
__global__ __launch_bounds__(256)
void qprep_kernel(const float* __restrict__ q, unsigned short* __restrict__ qs)
{
  const int gid = blockIdx.x * 256 + threadIdx.x;
  const int row = gid >> 7;
  const int c8  = (gid & 127) * 8;
  const float* src = q + (size_t)row * 1024 + c8;
  float4 f0 = *(const float4*)src;
  float4 f1 = *(const float4*)(src + 4);
  float vs[8] = {f0.x, f0.y, f0.z, f0.w, f1.x, f1.y, f1.z, f1.w};
  unsigned short h[8], l[8];
  #pragma unroll
  for (int i = 0; i < 8; ++i){ h[i] = f2bf(vs[i]); l[i] = f2bf(vs[i] - bf2f(h[i])); }
  uint4 hv, lv;
  hv.x=pack2(h[0],h[1]); hv.y=pack2(h[2],h[3]); hv.z=pack2(h[4],h[5]); hv.w=pack2(h[6],h[7]);
  lv.x=pack2(l[0],l[1]); lv.y=pack2(l[2],l[3]); lv.z=pack2(l[4],l[5]); lv.w=pack2(l[6],l[7]);
  size_t o = (size_t)row * 2048 + c8;
  *(uint4*)(qs + o)        = hv;
  *(uint4*)(qs + o + 1024) = lv;
}

// k[b][kv][e] f32 -> ksplit[b][kv][2048] = [k_h | k_l] and kT[b][e][kv] (hi)
__global__ __launch_bounds__(256)
void kprep_kernel(const float* __restrict__ kin, unsigned short* __restrict__ ks,
                  unsigned short* __restrict__ kT)
{
  __shared__ float tile[64][65];
  const int bz = blockIdx.z;
  const float* kb = kin + (size_t)bz * 2048 * 1024;
  unsigned short* ksb = ks + (size_t)bz * 2048 * 2048;
  unsigned short* kTb = kT + (size_t)bz * 1024 * 2048;
  const int kv0 = blockIdx.x * 64, e0 = blockIdx.y * 64;
  const int t = threadIdx.x;
  const int r = t >> 2, cq = t & 3;
  #pragma unroll
  for (int i = 0; i < 4; ++i){
    float4 f = *(const float4*)(kb + (size_t)(kv0 + r) * 1024 + e0 + cq*16 + i*4);
    unsigned short h0=f2bf(f.x), h1=f2bf(f.y), h2=f2bf(f.z), h3=f2bf(f.w);
    uint2 hv, lv;
    hv.x = pack2(h0, h1); hv.y = pack2(h2, h3);
    lv.x = pack2(f2bf(f.x - bf2f(h0)), f2bf(f.y - bf2f(h1)));
    lv.y = pack2(f2bf(f.z - bf2f(h2)), f2bf(f.w - bf2f(h3)));
    size_t o = (size_t)(kv0 + r) * 2048 + e0 + cq*16 + i*4;
    *(uint2*)(ksb + o)        = hv;
    *(uint2*)(ksb + o + 1024) = lv;
    tile[r][cq*16 + i*4 + 0] = f.x;
    tile[r][cq*16 + i*4 + 1] = f.y;
    tile[r][cq*16 + i*4 + 2] = f.z;
    tile[r][cq*16 + i*4 + 3] = f.w;
  }
  __syncthreads();
  unsigned short h[16];
  #pragma unroll
  for (int i = 0; i < 16; ++i) h[i] = f2bf(tile[cq*16 + i][r]);
  uint4 va, vb;
  va.x=pack2(h[0],h[1]);  va.y=pack2(h[2],h[3]);   va.z=pack2(h[4],h[5]);   va.w=pack2(h[6],h[7]);
  vb.x=pack2(h[8],h[9]);  vb.y=pack2(h[10],h[11]); vb.z=pack2(h[12],h[13]); vb.w=pack2(h[14],h[15]);
  size_t o = (size_t)(e0 + r) * 2048 + kv0 + cq*16;
  *(uint4*)(kTb + o)     = va;
  *(uint4*)(kTb + o + 8) = vb;
}

// exact row softmax over 2048 f32, then * mask, -> bf16
__global__ __launch_bounds__(256)
void softmax_kernel(const float* __restrict__ S, const int* __restrict__ mask,
                    unsigned short* __restrict__ P)
{
  const int row = blockIdx.x;
  const float* s = S + (size_t)row * 2048;
  const int* mk = mask + (size_t)row * 2048;
  unsigned short* p = P + (size_t)row * 2048;
  const int t = threadIdx.x;
  float4 v0 = ((const float4*)s)[t];
  float4 v1 = ((const float4*)s)[t + 256];
  float m = fmaxf(fmaxf(fmaxf(v0.x, v0.y), fmaxf(v0.z, v0.w)),
                  fmaxf(fmaxf(v1.x, v1.y), fmaxf(v1.z, v1.w)));
  #pragma unroll
  for (int off = 32; off > 0; off >>= 1) m = fmaxf(m, __shfl_xor(m, off));
  __shared__ float rmax[4], rsum[4];
  const int wid = t >> 6;
  if ((t & 63) == 0) rmax[wid] = m;
  __syncthreads();
  m = fmaxf(fmaxf(rmax[0], rmax[1]), fmaxf(rmax[2], rmax[3]));
  float e0 = __expf(v0.x - m), e1 = __expf(v0.y - m), e2 = __expf(v0.z - m), e3 = __expf(v0.w - m);
  float e4 = __expf(v1.x - m), e5 = __expf(v1.y - m), e6 = __expf(v1.z - m), e7 = __expf(v1.w - m);
  float ssum = ((e0 + e1) + (e2 + e3)) + ((e4 + e5) + (e6 + e7));
  #pragma unroll
  for (int off = 32; off > 0; off >>= 1) ssum += __shfl_xor(ssum, off);
  if ((t & 63) == 0) rsum[wid] = ssum;
  __syncthreads();
  float inv = 1.f / (rsum[0] + rsum[1] + rsum[2] + rsum[3]);
  int4 m0 = ((const int4*)mk)[t];
  int4 m1 = ((const int4*)mk)[t + 256];
  ushort4 o0, o1;
  o0.x = f2bf(e0 * inv * (float)m0.x);
  o0.y = f2bf(e1 * inv * (float)m0.y);
  o0.z = f2bf(e2 * inv * (float)m0.z);
  o0.w = f2bf(e3 * inv * (float)m0.w);
  o1.x = f2bf(e4 * inv * (float)m1.x);
  o1.y = f2bf(e5 * inv * (float)m1.y);
  o1.z = f2bf(e6 * inv * (float)m1.z);
  o1.w = f2bf(e7 * inv * (float)m1.w);
  ((ushort4*)p)[t]       = o0;
  ((ushort4*)p)[t + 256] = o1;
}

extern "C" void kernel_launch(void* const* d_in, const int* in_sizes, int n_in,
                              void* d_out, int out_size, void* d_ws, size_t ws_size,
                              hipStream_t stream)
{
  (void)in_sizes; (void)n_in; (void)out_size;
  const float* kin  = (const float*)d_in[0];
  const float* qin  = (const float*)d_in[1];
  const float* Win  = (const float*)d_in[2];
  const int*   mask = (const int*)d_in[3];

  // ws: Wt (4MB) | per-batch { qsplit 8 | qwsplit 8 | ksplit 8 | kT 4 | S 16 | P 8 } = 52MB
  int bpc = 1;
  {
    const size_t per_b = (size_t)2048*2048*2*3 + (size_t)1024*2048*2
                       + (size_t)2048*2048*4 + (size_t)2048*2048*2;
    const size_t fixed = (size_t)1024*2048*2;
    const int cands[5] = {16, 8, 4, 2, 1};
    for (int i = 0; i < 5; ++i){
      if (fixed + (size_t)cands[i] * per_b <= ws_size){ bpc = cands[i]; break; }
    }
  }
  unsigned short* Wt      = (unsigned short*)d_ws;
  unsigned short* qsplit  = Wt + (size_t)1024*2048;
  unsigned short* qwsplit = qsplit  + (size_t)bpc*2048*2048;
  unsigned short* ksplit  = qwsplit + (size_t)bpc*2048*2048;
  unsigned short* kT      = ksplit  + (size_t)bpc*2048*2048;
  float*          Sb      = (float*)(kT + (size_t)bpc*1024*2048);
  unsigned short* Pb      = (unsigned short*)(Sb + (size_t)bpc*2048*2048);

  wtprep_kernel<<<dim3(16, 16, 1), 256, 0, stream>>>(Win, Wt);

  for (int cb = 0; cb < 16; cb += bpc){
    qprep_kernel<<<dim3(bpc * 1024, 1, 1), 256, 0, stream>>>(
        qin + (size_t)cb * 2048 * 1024, qsplit);

    // K1: qw = q @ W  (3-pass split via remap, NT=48) -> qwsplit [h|l]
    gemm256<1, 1><<<dim3(bpc * 8, 4, 1), 512, 0, stream>>>(
        qsplit, Wt, qwsplit, 48, 2048, 2048, 0, 0, 0, 0);

    kprep_kernel<<<dim3(32, 16, bpc), 256, 0, stream>>>(
        kin + (size_t)cb * 2048 * 1024, ksplit, kT);

    // K2: S = qw @ k^T (3-pass split via remap, NT=48), batched
    gemm256<1, 0><<<dim3(8, 8, bpc), 512, 0, stream>>>(
        qwsplit, ksplit, Sb, 48, 2048, 2048, 2048,
        (long)2048 * 2048, (long)2048 * 2048, (long)2048 * 2048);

    // K3: row softmax * mask -> P (bf16)
    softmax_kernel<<<dim3(bpc * 2048, 1, 1), 256, 0, stream>>>(
        Sb, mask + (size_t)cb * 2048 * 2048, Pb);

    // K4: O = P @ kT^T (plain, NT=32), batched -> d_out
    gemm256<0, 0><<<dim3(8, 4, bpc), 512, 0, stream>>>(
        Pb, kT, (float*)d_out + (size_t)cb * 2048 * 1024, 32, 2048, 2048, 1024,
        (long)2048 * 2048, (long)1024 * 2048, (long)2048 * 1024);
  }
}

// Round 7
// 1001.042 us; speedup vs baseline: 1.6786x; 1.1416x over previous
//
#include <hip/hip_runtime.h>
#include <stdint.h>

typedef short bfrag __attribute__((ext_vector_type(8)));   // 8 bf16 (4 VGPR)
typedef float facc4 __attribute__((ext_vector_type(4)));   // MFMA accumulator

__device__ __forceinline__ unsigned short f2bf(float x){
  union { float f; uint32_t u; } v; v.f = x;
  uint32_t r = v.u + 0x7FFFu + ((v.u >> 16) & 1u);   // RNE
  return (unsigned short)(r >> 16);
}
__device__ __forceinline__ float bf2f(unsigned short h){
  union { uint32_t u; float f; } v; v.u = ((uint32_t)h) << 16; return v.f;
}
__device__ __forceinline__ uint32_t pack2(unsigned short a, unsigned short b){
  return (uint32_t)a | ((uint32_t)b << 16);
}

__device__ __forceinline__ void gload_lds16(const void* g, void* l){
  __builtin_amdgcn_global_load_lds(
      (const __attribute__((address_space(1))) void*)g,
      (__attribute__((address_space(3))) void*)l, 16, 0, 0);
}

// ---------------------------------------------------------------------------
// 256x256 8-phase bf16 GEMM (T3+T4+T5 on fragment-major LDS), 8 waves
// (2M x 4N), BK=64, 128 KB LDS dbuf (1 block/CU).
//
// LDS fragment-major: tile = 32 frags of 1KB, frag f=(rg,ks) in exact MFMA
// lane order; DMA write and ds_read_b128 both contiguous 1KB -> 0 conflicts
// (verified round 6: SQ_LDS_BANK_CONFLICT = 0).
//
// Schedule per K-tile t (buf cur=t&1), 4 phases, each ending in a barrier
// pair around a 16-MFMA cluster:
//   ph0: ds_read B(8)+A(4) | stage A13(t+1 -> buf^1)   [dead since t-1 end]
//   ph1: ds_read A(4)      | stage B (t+2 -> cur)      [B dead after ph0]
//   ph2: ds_read A(4)      | stage A02(t+2 -> cur)     [rg0-3,8-11 dead ph1]
//   ph3: ds_read A(4)      | vmcnt(6) gate for t+1 before trailing barrier
// vmcnt(6) leaves exactly tile t+2's {B4,A02} in flight (in-order retire
// guarantees t+1 fully landed). Never drains to 0 in steady state (T4).
//
// REMAP=1: A,B are [hi(1024)|lo(1024)], NT=48 encodes Ah*Bh+Ah*Bl+Al*Bh via
// akt=(kt<16?kt:kt-16), bkt=(kt<32?kt:kt-32). REMAP=0: plain, NT=K/64.
// OUT: 0 = f32 C. 1 = split write hi at [row*2048+col], lo at +1024.
// T1: bijective XCD swizzle (m204) on flattened block id.
// ---------------------------------------------------------------------------
template<int REMAP, int OUT>
__global__ __launch_bounds__(512, 1)
void gemm256(const unsigned short* __restrict__ A,
             const unsigned short* __restrict__ B,
             void* __restrict__ C,
             int NT, int lda, int ldb, int ldc,
             long abstr, long bbstr, long cbstr)
{
  __shared__ __align__(16) unsigned short lds[2][2][16384];   // 128 KB

  const int tid  = threadIdx.x;
  const int lane = tid & 63;
  const int wv   = tid >> 6;          // 0..7
  const int wm   = wv >> 2;           // 0..1  -> 128 rows
  const int wn   = wv & 3;            // 0..3  -> 64 cols

  // T1: bijective XCD-aware remap of the flattened block id (m204)
  const int gx = gridDim.x, gy = gridDim.y;
  const int nwg  = gx * gy * (int)gridDim.z;
  const int orig = blockIdx.x + gx * (blockIdx.y + gy * blockIdx.z);
  const int qd = nwg >> 3, rm = nwg & 7;
  const int xcd = orig & 7, idx = orig >> 3;
  const int swz = (xcd < rm ? xcd * (qd + 1) : rm * (qd + 1) + (xcd - rm) * qd) + idx;
  const int m0 = (swz % gx) * 256;
  const int rest = swz / gx;
  const int n0 = (rest % gy) * 256;
  const int z  = rest / gy;

  const unsigned short* Ab = A + (size_t)z * (size_t)abstr;
  const unsigned short* Bb = B + (size_t)z * (size_t)bbstr;

  const int fr  = lane & 15;
  const int fkc = lane >> 4;          // 0..3

  auto stageA = [&](int buf, int kt, int j){
    int akt = kt; if (REMAP) akt = (kt < 16) ? kt : kt - 16;
    const int f = j * 8 + wv, rg = f >> 1, ks = f & 1;
    gload_lds16(Ab + (size_t)(m0 + rg * 16 + fr) * lda + akt * 64 + ks * 32 + fkc * 8,
                &lds[buf][0][f * 512]);
  };
  auto stageB = [&](int buf, int kt, int j){
    int bkt = kt; if (REMAP) bkt = (kt < 32) ? kt : kt - 32;
    const int f = j * 8 + wv, rg = f >> 1, ks = f & 1;
    gload_lds16(Bb + (size_t)(n0 + rg * 16 + fr) * ldb + bkt * 64 + ks * 32 + fkc * 8,
                &lds[buf][1][f * 512]);
  };

  facc4 acc[8][4];
  #pragma unroll
  for (int a = 0; a < 8; ++a)
    #pragma unroll
    for (int b = 0; b < 4; ++b)
      acc[a][b] = (facc4){0.f, 0.f, 0.f, 0.f};

  // prologue: tile0 fully (8), tile1 B+A02 (6) -> 14 in flight; drain oldest 8
  #pragma unroll
  for (int j = 0; j < 4; ++j) stageB(0, 0, j);
  #pragma unroll
  for (int j = 0; j < 4; ++j) stageA(0, 0, j);
  if (NT > 1){
    #pragma unroll
    for (int j = 0; j < 4; ++j) stageB(1, 1, j);
    stageA(1, 1, 0); stageA(1, 1, 2);
  }
  asm volatile("s_waitcnt vmcnt(6)" ::: "memory");
  asm volatile("s_barrier" ::: "memory");

  for (int t = 0; t < NT; ++t){
    const int cur = t & 1;
    const unsigned short* la = lds[cur][0];
    const unsigned short* lb = lds[cur][1];
    bfrag bv[4][2];
    #pragma unroll
    for (int p = 0; p < 4; ++p){
      // --- ds_read subtile for THIS phase's MFMA ---
      if (p == 0){
        #pragma unroll
        for (int ni = 0; ni < 4; ++ni){
          bv[ni][0] = *(const bfrag*)(lb + ((((wn * 4 + ni) * 2) + 0) << 9) + lane * 8);
          bv[ni][1] = *(const bfrag*)(lb + ((((wn * 4 + ni) * 2) + 1) << 9) + lane * 8);
        }
      }
      const int mi0 = 2 * p, mi1 = 2 * p + 1;
      bfrag a00 = *(const bfrag*)(la + (((wm * 8 + mi0) * 2 + 0) << 9) + lane * 8);
      bfrag a01 = *(const bfrag*)(la + (((wm * 8 + mi0) * 2 + 1) << 9) + lane * 8);
      bfrag a10 = *(const bfrag*)(la + (((wm * 8 + mi1) * 2 + 0) << 9) + lane * 8);
      bfrag a11 = *(const bfrag*)(la + (((wm * 8 + mi1) * 2 + 1) << 9) + lane * 8);

      // --- stage issue (region-death-safe, see header) ---
      if (p == 0 && t + 1 < NT){ stageA(cur ^ 1, t + 1, 1); stageA(cur ^ 1, t + 1, 3); }
      if (p == 1 && t + 2 < NT){
        #pragma unroll
        for (int j = 0; j < 4; ++j) stageB(cur, t + 2, j);
      }
      if (p == 2 && t + 2 < NT){ stageA(cur, t + 2, 0); stageA(cur, t + 2, 2); }

      asm volatile("s_barrier" ::: "memory");

      __builtin_amdgcn_s_setprio(1);
      #pragma unroll
      for (int ni = 0; ni < 4; ++ni){
        acc[mi0][ni] = __builtin_amdgcn_mfma_f32_16x16x32_bf16(a00, bv[ni][0], acc[mi0][ni], 0, 0, 0);
        acc[mi0][ni] = __builtin_amdgcn_mfma_f32_16x16x32_bf16(a01, bv[ni][1], acc[mi0][ni], 0, 0, 0);
        acc[mi1][ni] = __builtin_amdgcn_mfma_f32_16x16x32_bf16(a10, bv[ni][0], acc[mi1][ni], 0, 0, 0);
        acc[mi1][ni] = __builtin_amdgcn_mfma_f32_16x16x32_bf16(a11, bv[ni][1], acc[mi1][ni], 0, 0, 0);
      }
      __builtin_amdgcn_s_setprio(0);

      if (p == 3 && t + 1 < NT){
        if (t + 1 < NT - 1) asm volatile("s_waitcnt vmcnt(6)" ::: "memory");
        else                asm volatile("s_waitcnt vmcnt(0)" ::: "memory");
      }
      asm volatile("s_barrier" ::: "memory");
    }
  }

  #pragma unroll
  for (int mi = 0; mi < 8; ++mi)
    #pragma unroll
    for (int ni = 0; ni < 4; ++ni)
      #pragma unroll
      for (int j = 0; j < 4; ++j){
        const int row = m0 + wm * 128 + mi * 16 + fkc * 4 + j;
        const int col = n0 + wn * 64 + ni * 16 + fr;
        const float v = acc[mi][ni][j];
        if constexpr (OUT == 0){
          ((float*)C)[(size_t)z * (size_t)cbstr + (size_t)row * ldc + col] = v;
        } else {
          unsigned short* o = (unsigned short*)C;
          const unsigned short h = f2bf(v);
          o[(size_t)row * 2048 + col]        = h;
          o[(size_t)row * 2048 + 1024 + col] = f2bf(v - bf2f(h));
        }
      }
}

// W[e][n] f32 -> Wt[n][2048] = [Wt_h | Wt_l] bf16
__global__ __launch_bounds__(256)
void wtprep_kernel(const float* __restrict__ W, unsigned short* __restrict__ Wt)
{
  __shared__ float tile[64][65];
  const int e0 = blockIdx.x * 64, n0 = blockIdx.y * 64;
  const int t = threadIdx.x;
  const int r = t >> 2, cq = t & 3;
  #pragma unroll
  for (int i = 0; i < 4; ++i){
    float4 f = *(const float4*)(W + (size_t)(e0 + r) * 1024 + n0 + cq*16 + i*4);
    tile[r][cq*16 + i*4 + 0] = f.x;
    tile[r][cq*16 + i*4 + 1] = f.y;
    tile[r][cq*16 + i*4 + 2] = f.z;
    tile[r][cq*16 + i*4 + 3] = f.w;
  }
  __syncthreads();
  unsigned short h[16], l[16];
  #pragma unroll
  for (int i = 0; i < 16; ++i){
    float v = tile[cq*16 + i][r];
    h[i] = f2bf(v);
    l[i] = f2bf(v - bf2f(h[i]));
  }
  uint4 ha, hb, la4, lb4;
  ha.x=pack2(h[0],h[1]);   ha.y=pack2(h[2],h[3]);   ha.z=pack2(h[4],h[5]);   ha.w=pack2(h[6],h[7]);
  hb.x=pack2(h[8],h[9]);   hb.y=pack2(h[10],h[11]); hb.z=pack2(h[12],h[13]); hb.w=pack2(h[14],h[15]);
  la4.x=pack2(l[0],l[1]);  la4.y=pack2(l[2],l[3]);  la4.z=pack2(l[4],l[5]);  la4.w=pack2(l[6],l[7]);
  lb4.x=pack2(l[8],l[9]);  lb4.y=pack2(l[10],l[11]);lb4.z=pack2(l[12],l[13]);lb4.w=pack2(l[14],l[15]);
  size_t o = (size_t)(n0 + r) * 2048 + e0 + cq*16;
  *(uint4*)(Wt + o)          = ha;
  *(uint4*)(Wt + o + 8)      = hb;
  *(uint4*)(Wt + o + 1024)   = la4;
  *(uint4*)(Wt + o + 1032)   = lb4;
}

// q rows f32 [R][1024] -> qsplit[R][2048] = [q_h | q_l]
__global__ __launch_bounds__(256)
void qprep_kernel(const float* __restrict__ q, unsigned short* __restrict__ qs)
{
  const int gid = blockIdx.x * 256 + threadIdx.x;
  const int row = gid >> 7;
  const int c8  = (gid & 127) * 8;
  const float* src = q + (size_t)row * 1024 + c8;
  float4 f0 = *(const float4*)src;
  float4 f1 = *(const float4*)(src + 4);
  float vs[8] = {f0.x, f0.y, f0.z, f0.w, f1.x, f1.y, f1.z, f1.w};
  unsigned short h[8], l[8];
  #pragma unroll
  for (int i = 0; i < 8; ++i){ h[i] = f2bf(vs[i]); l[i] = f2bf(vs[i] - bf2f(h[i])); }
  uint4 hv, lv;
  hv.x=pack2(h[0],h[1]); hv.y=pack2(h[2],h[3]); hv.z=pack2(h[4],h[5]); hv.w=pack2(h[6],h[7]);
  lv.x=pack2(l[0],l[1]); lv.y=pack2(l[2],l[3]); lv.z=pack2(l[4],l[5]); lv.w=pack2(l[6],l[7]);
  size_t o = (size_t)row * 2048 + c8;
  *(uint4*)(qs + o)        = hv;
  *(uint4*)(qs + o + 1024) = lv;
}

// k[b][kv][e] f32 -> ksplit[b][kv][2048] = [k_h | k_l] and kT[b][e][kv] (hi)
__global__ __launch_bounds__(256)
void kprep_kernel(const float* __restrict__ kin, unsigned short* __restrict__ ks,
                  unsigned short* __restrict__ kT)
{
  __shared__ float tile[64][65];
  const int bz = blockIdx.z;
  const float* kb = kin + (size_t)bz * 2048 * 1024;
  unsigned short* ksb = ks + (size_t)bz * 2048 * 2048;
  unsigned short* kTb = kT + (size_t)bz * 1024 * 2048;
  const int kv0 = blockIdx.x * 64, e0 = blockIdx.y * 64;
  const int t = threadIdx.x;
  const int r = t >> 2, cq = t & 3;
  #pragma unroll
  for (int i = 0; i < 4; ++i){
    float4 f = *(const float4*)(kb + (size_t)(kv0 + r) * 1024 + e0 + cq*16 + i*4);
    unsigned short h0=f2bf(f.x), h1=f2bf(f.y), h2=f2bf(f.z), h3=f2bf(f.w);
    uint2 hv, lv;
    hv.x = pack2(h0, h1); hv.y = pack2(h2, h3);
    lv.x = pack2(f2bf(f.x - bf2f(h0)), f2bf(f.y - bf2f(h1)));
    lv.y = pack2(f2bf(f.z - bf2f(h2)), f2bf(f.w - bf2f(h3)));
    size_t o = (size_t)(kv0 + r) * 2048 + e0 + cq*16 + i*4;
    *(uint2*)(ksb + o)        = hv;
    *(uint2*)(ksb + o + 1024) = lv;
    tile[r][cq*16 + i*4 + 0] = f.x;
    tile[r][cq*16 + i*4 + 1] = f.y;
    tile[r][cq*16 + i*4 + 2] = f.z;
    tile[r][cq*16 + i*4 + 3] = f.w;
  }
  __syncthreads();
  unsigned short h[16];
  #pragma unroll
  for (int i = 0; i < 16; ++i) h[i] = f2bf(tile[cq*16 + i][r]);
  uint4 va, vb;
  va.x=pack2(h[0],h[1]);  va.y=pack2(h[2],h[3]);   va.z=pack2(h[4],h[5]);   va.w=pack2(h[6],h[7]);
  vb.x=pack2(h[8],h[9]);  vb.y=pack2(h[10],h[11]); vb.z=pack2(h[12],h[13]); vb.w=pack2(h[14],h[15]);
  size_t o = (size_t)(e0 + r) * 2048 + kv0 + cq*16;
  *(uint4*)(kTb + o)     = va;
  *(uint4*)(kTb + o + 8) = vb;
}

// exact row softmax over 2048 f32, then * mask, -> bf16
__global__ __launch_bounds__(256)
void softmax_kernel(const float* __restrict__ S, const int* __restrict__ mask,
                    unsigned short* __restrict__ P)
{
  const int row = blockIdx.x;
  const float* s = S + (size_t)row * 2048;
  const int* mk = mask + (size_t)row * 2048;
  unsigned short* p = P + (size_t)row * 2048;
  const int t = threadIdx.x;
  float4 v0 = ((const float4*)s)[t];
  float4 v1 = ((const float4*)s)[t + 256];
  float m = fmaxf(fmaxf(fmaxf(v0.x, v0.y), fmaxf(v0.z, v0.w)),
                  fmaxf(fmaxf(v1.x, v1.y), fmaxf(v1.z, v1.w)));
  #pragma unroll
  for (int off = 32; off > 0; off >>= 1) m = fmaxf(m, __shfl_xor(m, off));
  __shared__ float rmax[4], rsum[4];
  const int wid = t >> 6;
  if ((t & 63) == 0) rmax[wid] = m;
  __syncthreads();
  m = fmaxf(fmaxf(rmax[0], rmax[1]), fmaxf(rmax[2], rmax[3]));
  float e0 = __expf(v0.x - m), e1 = __expf(v0.y - m), e2 = __expf(v0.z - m), e3 = __expf(v0.w - m);
  float e4 = __expf(v1.x - m), e5 = __expf(v1.y - m), e6 = __expf(v1.z - m), e7 = __expf(v1.w - m);
  float ssum = ((e0 + e1) + (e2 + e3)) + ((e4 + e5) + (e6 + e7));
  #pragma unroll
  for (int off = 32; off > 0; off >>= 1) ssum += __shfl_xor(ssum, off);
  if ((t & 63) == 0) rsum[wid] = ssum;
  __syncthreads();
  float inv = 1.f / (rsum[0] + rsum[1] + rsum[2] + rsum[3]);
  int4 m0 = ((const int4*)mk)[t];
  int4 m1 = ((const int4*)mk)[t + 256];
  ushort4 o0, o1;
  o0.x = f2bf(e0 * inv * (float)m0.x);
  o0.y = f2bf(e1 * inv * (float)m0.y);
  o0.z = f2bf(e2 * inv * (float)m0.z);
  o0.w = f2bf(e3 * inv * (float)m0.w);
  o1.x = f2bf(e4 * inv * (float)m1.x);
  o1.y = f2bf(e5 * inv * (float)m1.y);
  o1.z = f2bf(e6 * inv * (float)m1.z);
  o1.w = f2bf(e7 * inv * (float)m1.w);
  ((ushort4*)p)[t]       = o0;
  ((ushort4*)p)[t + 256] = o1;
}

extern "C" void kernel_launch(void* const* d_in, const int* in_sizes, int n_in,
                              void* d_out, int out_size, void* d_ws, size_t ws_size,
                              hipStream_t stream)
{
  (void)in_sizes; (void)n_in; (void)out_size;
  const float* kin  = (const float*)d_in[0];
  const float* qin  = (const float*)d_in[1];
  const float* Win  = (const float*)d_in[2];
  const int*   mask = (const int*)d_in[3];

  // ws: Wt (4MB) | per-batch { qsplit 8 | qwsplit 8 | ksplit 8 | kT 4 | S 16 | P 8 } = 52MB
  int bpc = 1;
  {
    const size_t per_b = (size_t)2048*2048*2*3 + (size_t)1024*2048*2
                       + (size_t)2048*2048*4 + (size_t)2048*2048*2;
    const size_t fixed = (size_t)1024*2048*2;
    const int cands[5] = {16, 8, 4, 2, 1};
    for (int i = 0; i < 5; ++i){
      if (fixed + (size_t)cands[i] * per_b <= ws_size){ bpc = cands[i]; break; }
    }
  }
  unsigned short* Wt      = (unsigned short*)d_ws;
  unsigned short* qsplit  = Wt + (size_t)1024*2048;
  unsigned short* qwsplit = qsplit  + (size_t)bpc*2048*2048;
  unsigned short* ksplit  = qwsplit + (size_t)bpc*2048*2048;
  unsigned short* kT      = ksplit  + (size_t)bpc*2048*2048;
  float*          Sb      = (float*)(kT + (size_t)bpc*1024*2048);
  unsigned short* Pb      = (unsigned short*)(Sb + (size_t)bpc*2048*2048);

  wtprep_kernel<<<dim3(16, 16, 1), 256, 0, stream>>>(Win, Wt);

  for (int cb = 0; cb < 16; cb += bpc){
    qprep_kernel<<<dim3(bpc * 1024, 1, 1), 256, 0, stream>>>(
        qin + (size_t)cb * 2048 * 1024, qsplit);

    // K1: qw = q @ W  (3-pass split via remap, NT=48) -> qwsplit [h|l]
    gemm256<1, 1><<<dim3(bpc * 8, 4, 1), 512, 0, stream>>>(
        qsplit, Wt, qwsplit, 48, 2048, 2048, 0, 0, 0, 0);

    kprep_kernel<<<dim3(32, 16, bpc), 256, 0, stream>>>(
        kin + (size_t)cb * 2048 * 1024, ksplit, kT);

    // K2: S = qw @ k^T (3-pass split via remap, NT=48), batched
    gemm256<1, 0><<<dim3(8, 8, bpc), 512, 0, stream>>>(
        qwsplit, ksplit, Sb, 48, 2048, 2048, 2048,
        (long)2048 * 2048, (long)2048 * 2048, (long)2048 * 2048);

    // K3: row softmax * mask -> P (bf16)
    softmax_kernel<<<dim3(bpc * 2048, 1, 1), 256, 0, stream>>>(
        Sb, mask + (size_t)cb * 2048 * 2048, Pb);

    // K4: O = P @ kT^T (plain, NT=32), batched -> d_out
    gemm256<0, 0><<<dim3(8, 4, bpc), 512, 0, stream>>>(
        Pb, kT, (float*)d_out + (size_t)cb * 2048 * 1024, 32, 2048, 2048, 1024,
        (long)2048 * 2048, (long)1024 * 2048, (long)2048 * 1024);
  }
}